// Round 2
// baseline (522.813 us; speedup 1.0000x reference)
//
#include <hip/hip_runtime.h>
#include <hip/hip_bf16.h>
#include <math.h>

#define LP 1000
#define NCMP 64

__device__ __forceinline__ float rcp_fast(float x) { return __builtin_amdgcn_rcpf(x); }

// ---------------- GEMM: Y[M,128] = (relu? X : X)[M,K] @ W[K,128] + b ----------------
// 32-row tile, 256 threads, thread = 4 rows x 4 cols. Safe for in-place Y==X
// (each block reads only its own rows, all reads precede the final stores).
template<bool RELU_IN>
__global__ __launch_bounds__(256) void gemm_n128(const float* X, const float* W,
                                                 const float* __restrict__ bias,
                                                 float* Y, int M, int K)
{
    __shared__ __align__(16) float Xs[32][33];
    __shared__ __align__(16) float Ws[32][128];
    const int t  = threadIdx.x;
    const int tr = t >> 5;          // 0..7
    const int tc = t & 31;          // 0..31
    const int r0 = tr * 4;
    const int c0 = tc * 4;
    const int rowbase = blockIdx.x * 32;
    float acc[4][4] = {};
    for (int k0 = 0; k0 < K; k0 += 32) {
        {   // stage X tile: 32x32 = 256 float4, one per thread
            int r = t >> 3, cb = (t & 7) << 2;
            int gr = rowbase + r;
            float4 v = make_float4(0.f, 0.f, 0.f, 0.f);
            if (gr < M) v = *(const float4*)(X + (long)gr * K + k0 + cb);
            if (RELU_IN) { v.x = fmaxf(v.x, 0.f); v.y = fmaxf(v.y, 0.f);
                           v.z = fmaxf(v.z, 0.f); v.w = fmaxf(v.w, 0.f); }
            Xs[r][cb] = v.x; Xs[r][cb + 1] = v.y; Xs[r][cb + 2] = v.z; Xs[r][cb + 3] = v.w;
        }
        #pragma unroll
        for (int u = 0; u < 4; ++u) {   // stage W tile: 32x128 = 1024 float4
            int s = t + u * 256;
            int r = s >> 5, cb = (s & 31) << 2;
            *(float4*)&Ws[r][cb] = *(const float4*)(W + (long)(k0 + r) * 128 + cb);
        }
        __syncthreads();
        #pragma unroll
        for (int kk = 0; kk < 32; ++kk) {
            float4 wv = *(const float4*)&Ws[kk][c0];
            float x0 = Xs[r0][kk], x1 = Xs[r0 + 1][kk], x2 = Xs[r0 + 2][kk], x3 = Xs[r0 + 3][kk];
            acc[0][0] = fmaf(x0, wv.x, acc[0][0]); acc[0][1] = fmaf(x0, wv.y, acc[0][1]);
            acc[0][2] = fmaf(x0, wv.z, acc[0][2]); acc[0][3] = fmaf(x0, wv.w, acc[0][3]);
            acc[1][0] = fmaf(x1, wv.x, acc[1][0]); acc[1][1] = fmaf(x1, wv.y, acc[1][1]);
            acc[1][2] = fmaf(x1, wv.z, acc[1][2]); acc[1][3] = fmaf(x1, wv.w, acc[1][3]);
            acc[2][0] = fmaf(x2, wv.x, acc[2][0]); acc[2][1] = fmaf(x2, wv.y, acc[2][1]);
            acc[2][2] = fmaf(x2, wv.z, acc[2][2]); acc[2][3] = fmaf(x2, wv.w, acc[2][3]);
            acc[3][0] = fmaf(x3, wv.x, acc[3][0]); acc[3][1] = fmaf(x3, wv.y, acc[3][1]);
            acc[3][2] = fmaf(x3, wv.z, acc[3][2]); acc[3][3] = fmaf(x3, wv.w, acc[3][3]);
        }
        __syncthreads();
    }
    float4 bv = *(const float4*)(bias + c0);
    #pragma unroll
    for (int i = 0; i < 4; ++i) {
        int row = rowbase + r0 + i;
        if (row < M) {
            float4 o;
            o.x = acc[i][0] + bv.x; o.y = acc[i][1] + bv.y;
            o.z = acc[i][2] + bv.z; o.w = acc[i][3] + bv.w;
            *(float4*)(Y + (long)row * 128 + c0) = o;
        }
    }
}

// ---------------- flash attention (fp32), TQ=32, TK=64, KV-split x2 ----------------
// grid (32 qtiles, 2 splits, 8 batch), 256 threads. Thread: S-tile 2r x 4c
// (cols interleaved {tc+16j}), O-tile 2r x 8d (d interleaved {4tc, 64+4tc}).
// V reuses K's LDS buffer (loaded to regs during softmax, stored after QK sync).
__global__ __launch_bounds__(256) void flash_k(const float* __restrict__ Q, const float* __restrict__ Kg,
                                               const float* __restrict__ Vg, float* __restrict__ Opart,
                                               float* __restrict__ mpart, float* __restrict__ lpart)
{
    __shared__ __align__(16) float Qs[32][132];
    __shared__ __align__(16) float KVs[64][132];
    __shared__ __align__(16) float Ps[32][68];
    const int t  = threadIdx.x;
    const int tr = t >> 4;      // 0..15 -> rows {2tr, 2tr+1}
    const int tc = t & 15;      // cols {tc+16j}, dcols {4tc, 64+4tc}
    const int qt = blockIdx.x, sp = blockIdx.y, b = blockIdx.z;
    const int q0 = qt * 32;
    const float SCALE = 0.08838834764831845f;   // 1/sqrt(128)
    const float L2E   = 1.4426950408889634f;

    #pragma unroll
    for (int u = 0; u < 4; ++u) {   // Q tile: 32x128 = 1024 float4
        int s = t + u * 256;
        int r = s >> 5, cb = (s & 31) << 2;
        float4 v = make_float4(0.f, 0.f, 0.f, 0.f);
        if (q0 + r < LP) v = *(const float4*)(Q + ((long)b * LP + q0 + r) * 128 + cb);
        Qs[r][cb] = v.x; Qs[r][cb + 1] = v.y; Qs[r][cb + 2] = v.z; Qs[r][cb + 3] = v.w;
    }
    float m_i[2] = { -3.0e38f, -3.0e38f };
    float l_i[2] = { 0.f, 0.f };
    float Oa[2][8] = {};

    for (int kt = sp * 8; kt < sp * 8 + 8; ++kt) {
        const int key0 = kt * 64;
        __syncthreads();                               // prev PV done with KVs/Ps
        #pragma unroll
        for (int u = 0; u < 8; ++u) {                  // K tile: 64x128 = 2048 float4
            int s = t + u * 256;
            int r = s >> 5, cb = (s & 31) << 2;
            float4 v = make_float4(0.f, 0.f, 0.f, 0.f);
            if (key0 + r < LP) v = *(const float4*)(Kg + ((long)b * LP + key0 + r) * 128 + cb);
            KVs[r][cb] = v.x; KVs[r][cb + 1] = v.y; KVs[r][cb + 2] = v.z; KVs[r][cb + 3] = v.w;
        }
        __syncthreads();
        float sacc[2][4] = {};
        #pragma unroll 4
        for (int d4 = 0; d4 < 32; ++d4) {
            float4 q0v = *(const float4*)&Qs[2 * tr][d4 << 2];
            float4 q1v = *(const float4*)&Qs[2 * tr + 1][d4 << 2];
            #pragma unroll
            for (int j = 0; j < 4; ++j) {
                float4 kv = *(const float4*)&KVs[tc + (j << 4)][d4 << 2];
                sacc[0][j] += q0v.x * kv.x + q0v.y * kv.y + q0v.z * kv.z + q0v.w * kv.w;
                sacc[1][j] += q1v.x * kv.x + q1v.y * kv.y + q1v.z * kv.z + q1v.w * kv.w;
            }
        }
        __syncthreads();                               // QK done reading KVs
        float4 vreg[8];
        #pragma unroll
        for (int u = 0; u < 8; ++u) {                  // V tile -> regs (in flight during softmax)
            int s = t + u * 256;
            int r = s >> 5, cb = (s & 31) << 2;
            float4 v = make_float4(0.f, 0.f, 0.f, 0.f);
            if (key0 + r < LP) v = *(const float4*)(Vg + ((long)b * LP + key0 + r) * 128 + cb);
            vreg[u] = v;
        }
        // scale + mask
        #pragma unroll
        for (int j = 0; j < 4; ++j) {
            bool valid = (key0 + tc + (j << 4)) < LP;
            #pragma unroll
            for (int i = 0; i < 2; ++i) {
                float sv = sacc[i][j] * SCALE;
                sacc[i][j] = valid ? sv : -3.0e38f;
            }
        }
        // online softmax (rows owned by 16-lane groups sharing tr)
        #pragma unroll
        for (int i = 0; i < 2; ++i) {
            float tm = fmaxf(fmaxf(sacc[i][0], sacc[i][1]), fmaxf(sacc[i][2], sacc[i][3]));
            tm = fmaxf(tm, __shfl_xor(tm, 1));
            tm = fmaxf(tm, __shfl_xor(tm, 2));
            tm = fmaxf(tm, __shfl_xor(tm, 4));
            tm = fmaxf(tm, __shfl_xor(tm, 8));
            float mnew  = fmaxf(m_i[i], tm);
            float alpha = exp2f((m_i[i] - mnew) * L2E);
            float ps = 0.f;
            #pragma unroll
            for (int j = 0; j < 4; ++j) {
                float p = exp2f((sacc[i][j] - mnew) * L2E);
                Ps[2 * tr + i][tc + (j << 4)] = p;
                ps += p;
            }
            ps += __shfl_xor(ps, 1);
            ps += __shfl_xor(ps, 2);
            ps += __shfl_xor(ps, 4);
            ps += __shfl_xor(ps, 8);
            l_i[i] = l_i[i] * alpha + ps;
            m_i[i] = mnew;
            #pragma unroll
            for (int j = 0; j < 8; ++j) Oa[i][j] *= alpha;
        }
        #pragma unroll
        for (int u = 0; u < 8; ++u) {                  // V regs -> LDS (overwrite K)
            int s = t + u * 256;
            int r = s >> 5, cb = (s & 31) << 2;
            KVs[r][cb] = vreg[u].x; KVs[r][cb + 1] = vreg[u].y;
            KVs[r][cb + 2] = vreg[u].z; KVs[r][cb + 3] = vreg[u].w;
        }
        __syncthreads();                               // V + Ps visible
        #pragma unroll 2
        for (int c = 0; c < 64; ++c) {                 // PV
            float4 va = *(const float4*)&KVs[c][tc << 2];
            float4 vb = *(const float4*)&KVs[c][64 + (tc << 2)];
            float p0 = Ps[2 * tr][c];
            float p1 = Ps[2 * tr + 1][c];
            Oa[0][0] = fmaf(p0, va.x, Oa[0][0]); Oa[0][1] = fmaf(p0, va.y, Oa[0][1]);
            Oa[0][2] = fmaf(p0, va.z, Oa[0][2]); Oa[0][3] = fmaf(p0, va.w, Oa[0][3]);
            Oa[0][4] = fmaf(p0, vb.x, Oa[0][4]); Oa[0][5] = fmaf(p0, vb.y, Oa[0][5]);
            Oa[0][6] = fmaf(p0, vb.z, Oa[0][6]); Oa[0][7] = fmaf(p0, vb.w, Oa[0][7]);
            Oa[1][0] = fmaf(p1, va.x, Oa[1][0]); Oa[1][1] = fmaf(p1, va.y, Oa[1][1]);
            Oa[1][2] = fmaf(p1, va.z, Oa[1][2]); Oa[1][3] = fmaf(p1, va.w, Oa[1][3]);
            Oa[1][4] = fmaf(p1, vb.x, Oa[1][4]); Oa[1][5] = fmaf(p1, vb.y, Oa[1][5]);
            Oa[1][6] = fmaf(p1, vb.z, Oa[1][6]); Oa[1][7] = fmaf(p1, vb.w, Oa[1][7]);
        }
    }
    #pragma unroll
    for (int i = 0; i < 2; ++i) {
        int row = q0 + 2 * tr + i;
        if (row < LP) {
            long base = (((long)sp * 8 + b) * LP + row) * 128;
            float4 oa = make_float4(Oa[i][0], Oa[i][1], Oa[i][2], Oa[i][3]);
            float4 ob = make_float4(Oa[i][4], Oa[i][5], Oa[i][6], Oa[i][7]);
            *(float4*)(Opart + base + (tc << 2)) = oa;
            *(float4*)(Opart + base + 64 + (tc << 2)) = ob;
            if (tc == 0) {
                mpart[((long)sp * 8 + b) * LP + row] = m_i[i];
                lpart[((long)sp * 8 + b) * LP + row] = l_i[i];
            }
        }
    }
}

// ---------------- merge the two KV-split partials ----------------
__global__ __launch_bounds__(256) void merge_k(const float* __restrict__ Opart, const float* __restrict__ mpart,
                                               const float* __restrict__ lpart, float* __restrict__ out)
{
    const float L2E = 1.4426950408889634f;
    int idx = blockIdx.x * 256 + threadIdx.x;   // < 1,024,000
    int row = idx >> 7;
    float m0 = mpart[row], m1 = mpart[row + 8000];
    float l0 = lpart[row], l1 = lpart[row + 8000];
    float m  = fmaxf(m0, m1);
    float w0 = exp2f((m0 - m) * L2E), w1 = exp2f((m1 - m) * L2E);
    float l  = w0 * l0 + w1 * l1;
    float o  = w0 * Opart[idx] + w1 * Opart[idx + 1024000];
    out[idx] = o / l;
}

// ---------------- A = sigmoid(P C^T), Asum accumulation ----------------
__global__ __launch_bounds__(256) void sigA_k(const float* __restrict__ P, const float* __restrict__ C,
                                              float* __restrict__ A, float* __restrict__ Asum)
{
    __shared__ __align__(16) float Psh[32][132];
    __shared__ __align__(16) float Csh[64][132];
    __shared__ float red[256];
    const int t  = threadIdx.x;
    const int tr = t >> 4, tc = t & 15;
    const int i0 = blockIdx.x * 32;
    const int b  = blockIdx.y;
    #pragma unroll
    for (int u = 0; u < 4; ++u) {
        int s = t + u * 256;
        int r = s >> 5, cb = (s & 31) << 2;
        float4 v = make_float4(0.f, 0.f, 0.f, 0.f);
        if (i0 + r < LP) v = *(const float4*)(P + ((long)b * LP + i0 + r) * 128 + cb);
        Psh[r][cb] = v.x; Psh[r][cb + 1] = v.y; Psh[r][cb + 2] = v.z; Psh[r][cb + 3] = v.w;
    }
    #pragma unroll
    for (int u = 0; u < 8; ++u) {
        int s = t + u * 256;
        int r = s >> 5, cb = (s & 31) << 2;
        float4 v = *(const float4*)(C + ((long)b * NCMP + r) * 128 + cb);
        Csh[r][cb] = v.x; Csh[r][cb + 1] = v.y; Csh[r][cb + 2] = v.z; Csh[r][cb + 3] = v.w;
    }
    __syncthreads();
    float sacc[2][4] = {};
    #pragma unroll 4
    for (int d4 = 0; d4 < 32; ++d4) {
        float4 p0 = *(const float4*)&Psh[2 * tr][d4 << 2];
        float4 p1 = *(const float4*)&Psh[2 * tr + 1][d4 << 2];
        #pragma unroll
        for (int j = 0; j < 4; ++j) {
            float4 cv = *(const float4*)&Csh[tc + (j << 4)][d4 << 2];
            sacc[0][j] += p0.x * cv.x + p0.y * cv.y + p0.z * cv.z + p0.w * cv.w;
            sacc[1][j] += p1.x * cv.x + p1.y * cv.y + p1.z * cv.z + p1.w * cv.w;
        }
    }
    const float L2E = 1.4426950408889634f;
    float lsum = 0.f;
    #pragma unroll
    for (int i = 0; i < 2; ++i) {
        int gi = i0 + 2 * tr + i;
        if (gi < LP) {
            #pragma unroll
            for (int j = 0; j < 4; ++j) {
                float sg = rcp_fast(1.f + exp2f(-sacc[i][j] * L2E));
                A[((long)b * LP + gi) * NCMP + tc + (j << 4)] = sg;
                lsum += sg;
            }
        }
    }
    red[t] = lsum;
    __syncthreads();
    for (int off = 128; off > 0; off >>= 1) {
        if (t < off) red[t] += red[t + off];
        __syncthreads();
    }
    if (t == 0) atomicAdd(Asum + b, red[0]);
}

// -------- cpe[b,d] += sum_{i,k} tanh(pf[b,i,d]*cf[b,k,d]) * A[b,i,k] (unnormalized) --------
__global__ __launch_bounds__(256) void cp_k(const float* __restrict__ pf, const float* __restrict__ cf,
                                            const float* __restrict__ A, float* __restrict__ cpe)
{
    __shared__ __align__(16) float Csh[64][128];
    __shared__ __align__(16) float Ash[25][64];
    __shared__ float red[256];
    const int t  = threadIdx.x;
    const int d  = t & 127;
    const int kh = t >> 7;          // 0..1
    const int i0 = blockIdx.x * 25; // 40 tiles x 25 = 1000
    const int b  = blockIdx.y;
    #pragma unroll
    for (int u = 0; u < 8; ++u) {   // compound feats tile 64x128
        int s = t + u * 256;
        int r = s >> 5, cb = (s & 31) << 2;
        *(float4*)&Csh[r][cb] = *(const float4*)(cf + ((long)b * NCMP + r) * 128 + cb);
    }
    for (int s = t; s < 400; s += 256)   // A tile 25x64 = 400 float4, contiguous
        ((float4*)&Ash[0][0])[s] = ((const float4*)(A + ((long)b * LP + i0) * NCMP))[s];
    __syncthreads();
    const float TWO_L2E = 2.8853900817779268f;   // 2*log2(e)
    float acc = 0.f;
    for (int ii = 0; ii < 25; ++ii) {
        float pv  = pf[((long)b * LP + i0 + ii) * 128 + d];
        float ptl = pv * TWO_L2E;
        #pragma unroll
        for (int kk = 0; kk < 32; ++kk) {
            int k = (kh << 5) + kk;
            float e  = exp2f(ptl * Csh[k][d]);          // exp(2x) as 2^(x*2log2e)
            float th = 1.f - 2.f * rcp_fast(e + 1.f);   // tanh(x)
            acc = fmaf(th, Ash[ii][k], acc);
        }
    }
    red[t] = acc;
    __syncthreads();
    if (t < 128) atomicAdd(cpe + (long)b * 128 + t, red[t] + red[t + 128]);
}

// ---------------- classifier MLP ----------------
__global__ __launch_bounds__(256) void mlp1_k(const float* __restrict__ cpe, const float* __restrict__ Asum,
                                              const float* __restrict__ W, const float* __restrict__ bias,
                                              float* __restrict__ out)
{
    int idx = blockIdx.x * 256 + threadIdx.x;  // 8192
    int b = idx >> 10, n = idx & 1023;
    float inv = 1.0f / Asum[b];
    float acc = 0.f;
    #pragma unroll 4
    for (int k = 0; k < 128; ++k) acc = fmaf(cpe[b * 128 + k], W[(long)k * 1024 + n], acc);
    out[idx] = fmaxf(fmaf(acc, inv, bias[n]), 0.f);
}

template<int K, int N, bool RELU>
__global__ __launch_bounds__(256) void mlp_mid_k(const float* __restrict__ in, const float* __restrict__ W,
                                                 const float* __restrict__ bias, float* __restrict__ out)
{
    int idx = blockIdx.x * 256 + threadIdx.x;
    int b = idx / N, n = idx % N;
    float acc = 0.f;
    #pragma unroll 4
    for (int k = 0; k < K; ++k) acc = fmaf(in[b * K + k], W[(long)k * N + n], acc);
    acc += bias[n];
    out[idx] = RELU ? fmaxf(acc, 0.f) : acc;
}

__global__ __launch_bounds__(256) void mlp4_k(const float* __restrict__ h3, const float* __restrict__ W,
                                              const float* __restrict__ bias, float* __restrict__ out)
{
    int t = threadIdx.x;
    int b = t >> 5, l = t & 31;
    float acc = 0.f;
    for (int k = l; k < 256; k += 32) acc = fmaf(h3[b * 256 + k], W[k], acc);
    #pragma unroll
    for (int off = 16; off > 0; off >>= 1) acc += __shfl_xor(acc, off);
    if (l == 0) out[b] = acc + bias[0];
}

extern "C" void kernel_launch(void* const* d_in, const int* in_sizes, int n_in,
                              void* d_out, int out_size, void* d_ws, size_t ws_size,
                              hipStream_t stream)
{
    const float* PE   = (const float*)d_in[0];
    const float* PFX  = (const float*)d_in[1];
    const float* CF   = (const float*)d_in[2];
    const float* emb_w = (const float*)d_in[3];  const float* emb_b = (const float*)d_in[4];
    const float* wq_w  = (const float*)d_in[5];  const float* wq_b  = (const float*)d_in[6];
    const float* wk_w  = (const float*)d_in[7];  const float* wk_b  = (const float*)d_in[8];
    const float* wv_w  = (const float*)d_in[9];  const float* wv_b  = (const float*)d_in[10];
    const float* wo_w  = (const float*)d_in[11]; const float* wo_b  = (const float*)d_in[12];
    const float* jp_w  = (const float*)d_in[13]; const float* jp_b  = (const float*)d_in[14];
    const float* jc_w  = (const float*)d_in[15]; const float* jc_b  = (const float*)d_in[16];
    const float* c1_w  = (const float*)d_in[17]; const float* c1_b  = (const float*)d_in[18];
    const float* c2_w  = (const float*)d_in[19]; const float* c2_b  = (const float*)d_in[20];
    const float* c3_w  = (const float*)d_in[21]; const float* c3_b  = (const float*)d_in[22];
    const float* c4_w  = (const float*)d_in[23]; const float* c4_b  = (const float*)d_in[24];

    float* ws     = (float*)d_ws;
    float* bufQ   = ws;                    // 1,024,000 (pe -> Q in place)
    float* bufK   = bufQ   + 1024000;      // 1,024,000
    float* bufV   = bufK   + 1024000;      // 1,024,000
    float* bufAtt = bufV   + 1024000;      // 1,024,000 (merge out -> wo in place)
    float* bufP   = bufAtt + 1024000;      // 1,024,000
    float* bufC   = bufP   + 1024000;      //    65,536
    float* bufA   = bufC   + 65536;        //   512,000
    float* Opart  = bufA   + 512000;       // 2,048,000
    float* mpart  = Opart  + 2048000;      //    16,000
    float* lpart  = mpart  + 16000;        //    16,000
    float* Asum   = lpart  + 16000;        //         8
    float* cpe    = Asum   + 8;            //     1,024
    float* h1     = cpe    + 1024;         //     8,192
    float* h2     = h1     + 8192;         //     8,192
    float* h3     = h2     + 8192;         //     2,048
    // total ~7.80M floats = ~29.8 MB

    hipMemsetAsync(Asum, 0, (8 + 1024) * sizeof(float), stream);

    gemm_n128<false><<<250, 256, 0, stream>>>(PE,    emb_w, emb_b, bufQ,   8000, 320); // pe
    gemm_n128<false><<<250, 256, 0, stream>>>(bufQ,  wq_w,  wq_b,  bufQ,   8000, 128); // Q (in place)
    gemm_n128<false><<<250, 256, 0, stream>>>(PFX,   wk_w,  wk_b,  bufK,   8000, 128); // K
    gemm_n128<false><<<250, 256, 0, stream>>>(PFX,   wv_w,  wv_b,  bufV,   8000, 128); // V
    flash_k<<<dim3(32, 2, 8), 256, 0, stream>>>(bufQ, bufK, bufV, Opart, mpart, lpart);
    merge_k<<<4000, 256, 0, stream>>>(Opart, mpart, lpart, bufAtt);
    gemm_n128<false><<<250, 256, 0, stream>>>(bufAtt, wo_w, wo_b, bufAtt, 8000, 128); // protein_feats
    gemm_n128<true ><<<250, 256, 0, stream>>>(bufAtt, jp_w, jp_b, bufP,   8000, 128); // P
    gemm_n128<true ><<<16,  256, 0, stream>>>(CF,     jc_w, jc_b, bufC,    512, 128); // C
    sigA_k<<<dim3(32, 8), 256, 0, stream>>>(bufP, bufC, bufA, Asum);
    cp_k<<<dim3(40, 8), 256, 0, stream>>>(bufAtt, CF, bufA, cpe);
    mlp1_k<<<32, 256, 0, stream>>>(cpe, Asum, c1_w, c1_b, h1);
    mlp_mid_k<1024, 1024, true><<<32, 256, 0, stream>>>(h1, c2_w, c2_b, h2);
    mlp_mid_k<1024, 256,  true><<<8,  256, 0, stream>>>(h2, c3_w, c3_b, h3);
    mlp4_k<<<1, 256, 0, stream>>>(h3, c4_w, c4_b, (float*)d_out);
}

// Round 3
// 360.851 us; speedup vs baseline: 1.4488x; 1.4488x over previous
//
#include <hip/hip_runtime.h>
#include <hip/hip_bf16.h>
#include <math.h>

#define LP 1000
#define NCMP 64

__device__ __forceinline__ float rcp_fast(float x) { return __builtin_amdgcn_rcpf(x); }

// ---------------- GEMM: Y[M,128] = op(X)[M,K] @ W[K,128] + b ----------------
// 32-row tile, 256 threads, thread = 4 rows x 4 cols. X staged TRANSPOSED in
// LDS (Xt[k][r]) so the inner loop is 2x ds_read_b128 per 16 FMA.
// MERGE: X is Opart (KV-split flash partials); X-load applies the m/l merge.
// In-place safe (block reads only its own 32 rows; stores after all reads).
// Requires M % 32 == 0 (holds: 8000, 512).
template<bool RELU_IN, bool MERGE>
__global__ __launch_bounds__(256) void gemm2(const float* X, const float* X2,
                                             const float* __restrict__ mp, const float* __restrict__ lp,
                                             const float* W, const float* __restrict__ bias,
                                             float* Y, int M, int K)
{
    __shared__ __align__(16) float Ws[32][128];   // 16.4 KB
    __shared__ __align__(16) float Xt[32][36];    // [k][r], stride 36 floats (144B, 16B-aligned)
    const int t  = threadIdx.x;
    const int r0 = (t >> 5) * 4;    // 4 rows
    const int c0 = (t & 31) * 4;    // 4 cols
    const int rowbase = blockIdx.x * 32;
    const float L2E = 1.4426950408889634f;
    float acc[4][4] = {};
    for (int k0 = 0; k0 < K; k0 += 32) {
        {   // stage X tile 32x32, transposed into Xt
            int r = t >> 3, k4 = (t & 7) << 2;
            int row = rowbase + r;
            float4 v;
            if (MERGE) {
                long idx = (long)row * 128 + k0 + k4;
                float m0 = mp[row], m1 = mp[row + 8000];
                float l0 = lp[row], l1 = lp[row + 8000];
                float m  = fmaxf(m0, m1);
                float w0 = exp2f((m0 - m) * L2E), w1 = exp2f((m1 - m) * L2E);
                float linv = 1.0f / (w0 * l0 + w1 * l1);
                float4 a = *(const float4*)(X + idx);
                float4 b = *(const float4*)(X2 + idx);
                v.x = (w0 * a.x + w1 * b.x) * linv;
                v.y = (w0 * a.y + w1 * b.y) * linv;
                v.z = (w0 * a.z + w1 * b.z) * linv;
                v.w = (w0 * a.w + w1 * b.w) * linv;
            } else {
                v = *(const float4*)(X + (long)row * K + k0 + k4);
            }
            if (RELU_IN) { v.x = fmaxf(v.x, 0.f); v.y = fmaxf(v.y, 0.f);
                           v.z = fmaxf(v.z, 0.f); v.w = fmaxf(v.w, 0.f); }
            Xt[k4 + 0][r] = v.x; Xt[k4 + 1][r] = v.y;
            Xt[k4 + 2][r] = v.z; Xt[k4 + 3][r] = v.w;
        }
        #pragma unroll
        for (int u = 0; u < 4; ++u) {   // stage W tile 32x128
            int s = t + u * 256;
            int r = s >> 5, cb = (s & 31) << 2;
            *(float4*)&Ws[r][cb] = *(const float4*)(W + (long)(k0 + r) * 128 + cb);
        }
        __syncthreads();
        #pragma unroll
        for (int kk = 0; kk < 32; ++kk) {
            float4 wv = *(const float4*)&Ws[kk][c0];
            float4 xv = *(const float4*)&Xt[kk][r0];
            acc[0][0] = fmaf(xv.x, wv.x, acc[0][0]); acc[0][1] = fmaf(xv.x, wv.y, acc[0][1]);
            acc[0][2] = fmaf(xv.x, wv.z, acc[0][2]); acc[0][3] = fmaf(xv.x, wv.w, acc[0][3]);
            acc[1][0] = fmaf(xv.y, wv.x, acc[1][0]); acc[1][1] = fmaf(xv.y, wv.y, acc[1][1]);
            acc[1][2] = fmaf(xv.y, wv.z, acc[1][2]); acc[1][3] = fmaf(xv.y, wv.w, acc[1][3]);
            acc[2][0] = fmaf(xv.z, wv.x, acc[2][0]); acc[2][1] = fmaf(xv.z, wv.y, acc[2][1]);
            acc[2][2] = fmaf(xv.z, wv.z, acc[2][2]); acc[2][3] = fmaf(xv.z, wv.w, acc[2][3]);
            acc[3][0] = fmaf(xv.w, wv.x, acc[3][0]); acc[3][1] = fmaf(xv.w, wv.y, acc[3][1]);
            acc[3][2] = fmaf(xv.w, wv.z, acc[3][2]); acc[3][3] = fmaf(xv.w, wv.w, acc[3][3]);
        }
        __syncthreads();
    }
    float4 bv = *(const float4*)(bias + c0);
    #pragma unroll
    for (int i = 0; i < 4; ++i) {
        int row = rowbase + r0 + i;
        float4 o;
        o.x = acc[i][0] + bv.x; o.y = acc[i][1] + bv.y;
        o.z = acc[i][2] + bv.z; o.w = acc[i][3] + bv.w;
        *(float4*)(Y + (long)row * 128 + c0) = o;
    }
}

// ---------------- flash attention (fp32), TQ=32, TK=64, KV-split x2 ----------------
__global__ __launch_bounds__(256) void flash_k(const float* __restrict__ Q, const float* __restrict__ Kg,
                                               const float* __restrict__ Vg, float* __restrict__ Opart,
                                               float* __restrict__ mpart, float* __restrict__ lpart)
{
    __shared__ __align__(16) float Qs[32][132];
    __shared__ __align__(16) float KVs[64][132];
    __shared__ __align__(16) float Ps[32][68];
    const int t  = threadIdx.x;
    const int tr = t >> 4;      // 0..15 -> rows {2tr, 2tr+1}
    const int tc = t & 15;      // cols {tc+16j}, dcols {4tc, 64+4tc}
    const int qt = blockIdx.x, sp = blockIdx.y, b = blockIdx.z;
    const int q0 = qt * 32;
    const float SCALE = 0.08838834764831845f;   // 1/sqrt(128)
    const float L2E   = 1.4426950408889634f;

    #pragma unroll
    for (int u = 0; u < 4; ++u) {   // Q tile: 32x128
        int s = t + u * 256;
        int r = s >> 5, cb = (s & 31) << 2;
        float4 v = make_float4(0.f, 0.f, 0.f, 0.f);
        if (q0 + r < LP) v = *(const float4*)(Q + ((long)b * LP + q0 + r) * 128 + cb);
        Qs[r][cb] = v.x; Qs[r][cb + 1] = v.y; Qs[r][cb + 2] = v.z; Qs[r][cb + 3] = v.w;
    }
    float m_i[2] = { -3.0e38f, -3.0e38f };
    float l_i[2] = { 0.f, 0.f };
    float Oa[2][8] = {};

    for (int kt = sp * 8; kt < sp * 8 + 8; ++kt) {
        const int key0 = kt * 64;
        __syncthreads();
        #pragma unroll
        for (int u = 0; u < 8; ++u) {                  // K tile: 64x128
            int s = t + u * 256;
            int r = s >> 5, cb = (s & 31) << 2;
            float4 v = make_float4(0.f, 0.f, 0.f, 0.f);
            if (key0 + r < LP) v = *(const float4*)(Kg + ((long)b * LP + key0 + r) * 128 + cb);
            KVs[r][cb] = v.x; KVs[r][cb + 1] = v.y; KVs[r][cb + 2] = v.z; KVs[r][cb + 3] = v.w;
        }
        __syncthreads();
        float sacc[2][4] = {};
        #pragma unroll 4
        for (int d4 = 0; d4 < 32; ++d4) {
            float4 q0v = *(const float4*)&Qs[2 * tr][d4 << 2];
            float4 q1v = *(const float4*)&Qs[2 * tr + 1][d4 << 2];
            #pragma unroll
            for (int j = 0; j < 4; ++j) {
                float4 kv = *(const float4*)&KVs[tc + (j << 4)][d4 << 2];
                sacc[0][j] += q0v.x * kv.x + q0v.y * kv.y + q0v.z * kv.z + q0v.w * kv.w;
                sacc[1][j] += q1v.x * kv.x + q1v.y * kv.y + q1v.z * kv.z + q1v.w * kv.w;
            }
        }
        __syncthreads();
        float4 vreg[8];
        #pragma unroll
        for (int u = 0; u < 8; ++u) {                  // V tile -> regs
            int s = t + u * 256;
            int r = s >> 5, cb = (s & 31) << 2;
            float4 v = make_float4(0.f, 0.f, 0.f, 0.f);
            if (key0 + r < LP) v = *(const float4*)(Vg + ((long)b * LP + key0 + r) * 128 + cb);
            vreg[u] = v;
        }
        #pragma unroll
        for (int j = 0; j < 4; ++j) {
            bool valid = (key0 + tc + (j << 4)) < LP;
            #pragma unroll
            for (int i = 0; i < 2; ++i) {
                float sv = sacc[i][j] * SCALE;
                sacc[i][j] = valid ? sv : -3.0e38f;
            }
        }
        #pragma unroll
        for (int i = 0; i < 2; ++i) {
            float tm = fmaxf(fmaxf(sacc[i][0], sacc[i][1]), fmaxf(sacc[i][2], sacc[i][3]));
            tm = fmaxf(tm, __shfl_xor(tm, 1));
            tm = fmaxf(tm, __shfl_xor(tm, 2));
            tm = fmaxf(tm, __shfl_xor(tm, 4));
            tm = fmaxf(tm, __shfl_xor(tm, 8));
            float mnew  = fmaxf(m_i[i], tm);
            float alpha = exp2f((m_i[i] - mnew) * L2E);
            float ps = 0.f;
            #pragma unroll
            for (int j = 0; j < 4; ++j) {
                float p = exp2f((sacc[i][j] - mnew) * L2E);
                Ps[2 * tr + i][tc + (j << 4)] = p;
                ps += p;
            }
            ps += __shfl_xor(ps, 1);
            ps += __shfl_xor(ps, 2);
            ps += __shfl_xor(ps, 4);
            ps += __shfl_xor(ps, 8);
            l_i[i] = l_i[i] * alpha + ps;
            m_i[i] = mnew;
            #pragma unroll
            for (int j = 0; j < 8; ++j) Oa[i][j] *= alpha;
        }
        #pragma unroll
        for (int u = 0; u < 8; ++u) {                  // V regs -> LDS (overwrite K)
            int s = t + u * 256;
            int r = s >> 5, cb = (s & 31) << 2;
            KVs[r][cb] = vreg[u].x; KVs[r][cb + 1] = vreg[u].y;
            KVs[r][cb + 2] = vreg[u].z; KVs[r][cb + 3] = vreg[u].w;
        }
        __syncthreads();
        #pragma unroll 2
        for (int c = 0; c < 64; ++c) {                 // PV
            float4 va = *(const float4*)&KVs[c][tc << 2];
            float4 vb = *(const float4*)&KVs[c][64 + (tc << 2)];
            float p0 = Ps[2 * tr][c];
            float p1 = Ps[2 * tr + 1][c];
            Oa[0][0] = fmaf(p0, va.x, Oa[0][0]); Oa[0][1] = fmaf(p0, va.y, Oa[0][1]);
            Oa[0][2] = fmaf(p0, va.z, Oa[0][2]); Oa[0][3] = fmaf(p0, va.w, Oa[0][3]);
            Oa[0][4] = fmaf(p0, vb.x, Oa[0][4]); Oa[0][5] = fmaf(p0, vb.y, Oa[0][5]);
            Oa[0][6] = fmaf(p0, vb.z, Oa[0][6]); Oa[0][7] = fmaf(p0, vb.w, Oa[0][7]);
            Oa[1][0] = fmaf(p1, va.x, Oa[1][0]); Oa[1][1] = fmaf(p1, va.y, Oa[1][1]);
            Oa[1][2] = fmaf(p1, va.z, Oa[1][2]); Oa[1][3] = fmaf(p1, va.w, Oa[1][3]);
            Oa[1][4] = fmaf(p1, vb.x, Oa[1][4]); Oa[1][5] = fmaf(p1, vb.y, Oa[1][5]);
            Oa[1][6] = fmaf(p1, vb.z, Oa[1][6]); Oa[1][7] = fmaf(p1, vb.w, Oa[1][7]);
        }
    }
    #pragma unroll
    for (int i = 0; i < 2; ++i) {
        int row = q0 + 2 * tr + i;
        if (row < LP) {
            long base = (((long)sp * 8 + b) * LP + row) * 128;
            float4 oa = make_float4(Oa[i][0], Oa[i][1], Oa[i][2], Oa[i][3]);
            float4 ob = make_float4(Oa[i][4], Oa[i][5], Oa[i][6], Oa[i][7]);
            *(float4*)(Opart + base + (tc << 2)) = oa;
            *(float4*)(Opart + base + 64 + (tc << 2)) = ob;
            if (tc == 0) {
                mpart[((long)sp * 8 + b) * LP + row] = m_i[i];
                lpart[((long)sp * 8 + b) * LP + row] = l_i[i];
            }
        }
    }
}

// ---------------- A = sigmoid(P C^T), Asum accumulation ----------------
__global__ __launch_bounds__(256) void sigA_k(const float* __restrict__ P, const float* __restrict__ C,
                                              float* __restrict__ A, float* __restrict__ Asum)
{
    __shared__ __align__(16) float Psh[32][132];
    __shared__ __align__(16) float Csh[64][132];
    __shared__ float red[256];
    const int t  = threadIdx.x;
    const int tr = t >> 4, tc = t & 15;
    const int i0 = blockIdx.x * 32;
    const int b  = blockIdx.y;
    #pragma unroll
    for (int u = 0; u < 4; ++u) {
        int s = t + u * 256;
        int r = s >> 5, cb = (s & 31) << 2;
        float4 v = make_float4(0.f, 0.f, 0.f, 0.f);
        if (i0 + r < LP) v = *(const float4*)(P + ((long)b * LP + i0 + r) * 128 + cb);
        Psh[r][cb] = v.x; Psh[r][cb + 1] = v.y; Psh[r][cb + 2] = v.z; Psh[r][cb + 3] = v.w;
    }
    #pragma unroll
    for (int u = 0; u < 8; ++u) {
        int s = t + u * 256;
        int r = s >> 5, cb = (s & 31) << 2;
        float4 v = *(const float4*)(C + ((long)b * NCMP + r) * 128 + cb);
        Csh[r][cb] = v.x; Csh[r][cb + 1] = v.y; Csh[r][cb + 2] = v.z; Csh[r][cb + 3] = v.w;
    }
    __syncthreads();
    float sacc[2][4] = {};
    #pragma unroll 4
    for (int d4 = 0; d4 < 32; ++d4) {
        float4 p0 = *(const float4*)&Psh[2 * tr][d4 << 2];
        float4 p1 = *(const float4*)&Psh[2 * tr + 1][d4 << 2];
        #pragma unroll
        for (int j = 0; j < 4; ++j) {
            float4 cv = *(const float4*)&Csh[tc + (j << 4)][d4 << 2];
            sacc[0][j] += p0.x * cv.x + p0.y * cv.y + p0.z * cv.z + p0.w * cv.w;
            sacc[1][j] += p1.x * cv.x + p1.y * cv.y + p1.z * cv.z + p1.w * cv.w;
        }
    }
    const float L2E = 1.4426950408889634f;
    float lsum = 0.f;
    #pragma unroll
    for (int i = 0; i < 2; ++i) {
        int gi = i0 + 2 * tr + i;
        if (gi < LP) {
            #pragma unroll
            for (int j = 0; j < 4; ++j) {
                float sg = rcp_fast(1.f + exp2f(-sacc[i][j] * L2E));
                A[((long)b * LP + gi) * NCMP + tc + (j << 4)] = sg;
                lsum += sg;
            }
        }
    }
    red[t] = lsum;
    __syncthreads();
    for (int off = 128; off > 0; off >>= 1) {
        if (t < off) red[t] += red[t + off];
        __syncthreads();
    }
    if (t == 0) atomicAdd(Asum + b, red[0]);
}

// -------- cpe[b,d] += sum_{i,k} tanh(pf[b,i,d]*cf[b,k,d]) * A[b,i,k] (unnormalized) --------
__global__ __launch_bounds__(256) void cp_k(const float* __restrict__ pf, const float* __restrict__ cf,
                                            const float* __restrict__ A, float* __restrict__ cpe)
{
    __shared__ __align__(16) float Csh[64][128];
    __shared__ __align__(16) float Ash[25][64];
    __shared__ float red[256];
    const int t  = threadIdx.x;
    const int d  = t & 127;
    const int kh = t >> 7;          // 0..1
    const int i0 = blockIdx.x * 25; // 40 tiles x 25 = 1000
    const int b  = blockIdx.y;
    #pragma unroll
    for (int u = 0; u < 8; ++u) {   // compound feats tile 64x128
        int s = t + u * 256;
        int r = s >> 5, cb = (s & 31) << 2;
        *(float4*)&Csh[r][cb] = *(const float4*)(cf + ((long)b * NCMP + r) * 128 + cb);
    }
    for (int s = t; s < 400; s += 256)   // A tile 25x64
        ((float4*)&Ash[0][0])[s] = ((const float4*)(A + ((long)b * LP + i0) * NCMP))[s];
    __syncthreads();
    const float TWO_L2E = 2.8853900817779268f;   // 2*log2(e)
    float acc = 0.f;
    for (int ii = 0; ii < 25; ++ii) {
        float pv  = pf[((long)b * LP + i0 + ii) * 128 + d];
        float ptl = pv * TWO_L2E;
        #pragma unroll
        for (int kk = 0; kk < 32; ++kk) {
            int k = (kh << 5) + kk;
            float e  = exp2f(ptl * Csh[k][d]);          // exp(2x)
            float th = 1.f - 2.f * rcp_fast(e + 1.f);   // tanh(x)
            acc = fmaf(th, Ash[ii][k], acc);
        }
    }
    red[t] = acc;
    __syncthreads();
    if (t < 128) atomicAdd(cpe + (long)b * 128 + t, red[t] + red[t + 128]);
}

// ---------------- classifier MLP: split-K partial kernels + finalize ----------------
// c1: [8,128] @ [128,1024] with per-b 1/Asum scaling folded into the input slab.
__global__ __launch_bounds__(256) void c1_part_k(const float* __restrict__ cpe, const float* __restrict__ Asum,
                                                 const float* __restrict__ W, float* __restrict__ part)
{
    __shared__ float ins[8][8];
    const int t = threadIdx.x, ks = blockIdx.x, k0 = ks * 8;
    if (t < 64) {
        int b = t >> 3, kk = t & 7;
        ins[b][kk] = cpe[b * 128 + k0 + kk] * (1.0f / Asum[b]);
    }
    __syncthreads();
    const int n = (t & 63) * 4 + (t >> 6) * 256;
    float4 acc[8] = {};
    #pragma unroll
    for (int kk = 0; kk < 8; ++kk) {
        float4 w4 = *(const float4*)(W + (long)(k0 + kk) * 1024 + n);
        #pragma unroll
        for (int b = 0; b < 8; ++b) {
            float s = ins[b][kk];
            acc[b].x = fmaf(s, w4.x, acc[b].x); acc[b].y = fmaf(s, w4.y, acc[b].y);
            acc[b].z = fmaf(s, w4.z, acc[b].z); acc[b].w = fmaf(s, w4.w, acc[b].w);
        }
    }
    #pragma unroll
    for (int b = 0; b < 8; ++b)
        *(float4*)(part + ((long)(ks * 8 + b)) * 1024 + n) = acc[b];
}

// c2: [8,1024] @ [1024,1024]
__global__ __launch_bounds__(256) void c2_part_k(const float* __restrict__ in, const float* __restrict__ W,
                                                 float* __restrict__ part)
{
    __shared__ float ins[8][16];
    const int t = threadIdx.x, ks = blockIdx.x, k0 = ks * 16;
    if (t < 128) {
        int b = t >> 4, kk = t & 15;
        ins[b][kk] = in[b * 1024 + k0 + kk];
    }
    __syncthreads();
    const int n = (t & 63) * 4 + (t >> 6) * 256;
    float4 acc[8] = {};
    #pragma unroll
    for (int kk = 0; kk < 16; ++kk) {
        float4 w4 = *(const float4*)(W + (long)(k0 + kk) * 1024 + n);
        #pragma unroll
        for (int b = 0; b < 8; ++b) {
            float s = ins[b][kk];
            acc[b].x = fmaf(s, w4.x, acc[b].x); acc[b].y = fmaf(s, w4.y, acc[b].y);
            acc[b].z = fmaf(s, w4.z, acc[b].z); acc[b].w = fmaf(s, w4.w, acc[b].w);
        }
    }
    #pragma unroll
    for (int b = 0; b < 8; ++b)
        *(float4*)(part + ((long)(ks * 8 + b)) * 1024 + n) = acc[b];
}

// c3: [8,1024] @ [1024,256]; thread quarter (t>>6) is an extra k-subsplit.
__global__ __launch_bounds__(256) void c3_part_k(const float* __restrict__ in, const float* __restrict__ W,
                                                 float* __restrict__ part)
{
    __shared__ float ins[8][64];
    const int t = threadIdx.x, bid = blockIdx.x;
    {
        int s0 = t, b = s0 >> 6, kk = s0 & 63;
        ins[b][kk] = in[b * 1024 + bid * 64 + kk];
        int s1 = t + 256; b = s1 >> 6; kk = s1 & 63;
        ins[b][kk] = in[b * 1024 + bid * 64 + kk];
    }
    __syncthreads();
    const int kq = t >> 6;                 // 0..3
    const int n  = (t & 63) * 4;
    const int kbase = bid * 64 + kq * 16;
    float4 acc[8] = {};
    #pragma unroll
    for (int kk = 0; kk < 16; ++kk) {
        float4 w4 = *(const float4*)(W + (long)(kbase + kk) * 256 + n);
        #pragma unroll
        for (int b = 0; b < 8; ++b) {
            float s = ins[b][kq * 16 + kk];
            acc[b].x = fmaf(s, w4.x, acc[b].x); acc[b].y = fmaf(s, w4.y, acc[b].y);
            acc[b].z = fmaf(s, w4.z, acc[b].z); acc[b].w = fmaf(s, w4.w, acc[b].w);
        }
    }
    const int ks = bid * 4 + kq;           // 0..63
    #pragma unroll
    for (int b = 0; b < 8; ++b)
        *(float4*)(part + ((long)(ks * 8 + b)) * 256 + n) = acc[b];
}

// finalize: out[idx] = relu(sum_ks part[ks][idx] + bias[n]); TOT = 8*N
template<int N, int KS>
__global__ __launch_bounds__(256) void mlp_fin_k(const float* __restrict__ part, const float* __restrict__ bias,
                                                 float* __restrict__ out)
{
    int idx = blockIdx.x * 256 + threadIdx.x;   // < 8*N
    int n = idx % N;
    float acc = 0.f;
    #pragma unroll 4
    for (int ks = 0; ks < KS; ++ks) acc += part[(long)ks * 8 * N + idx];
    out[idx] = fmaxf(acc + bias[n], 0.f);
}

__global__ __launch_bounds__(256) void mlp4_k(const float* __restrict__ h3, const float* __restrict__ W,
                                              const float* __restrict__ bias, float* __restrict__ out)
{
    int t = threadIdx.x;
    int b = t >> 5, l = t & 31;
    float acc = 0.f;
    for (int k = l; k < 256; k += 32) acc = fmaf(h3[b * 256 + k], W[k], acc);
    #pragma unroll
    for (int off = 16; off > 0; off >>= 1) acc += __shfl_xor(acc, off);
    if (l == 0) out[b] = acc + bias[0];
}

extern "C" void kernel_launch(void* const* d_in, const int* in_sizes, int n_in,
                              void* d_out, int out_size, void* d_ws, size_t ws_size,
                              hipStream_t stream)
{
    const float* PE   = (const float*)d_in[0];
    const float* PFX  = (const float*)d_in[1];
    const float* CF   = (const float*)d_in[2];
    const float* emb_w = (const float*)d_in[3];  const float* emb_b = (const float*)d_in[4];
    const float* wq_w  = (const float*)d_in[5];  const float* wq_b  = (const float*)d_in[6];
    const float* wk_w  = (const float*)d_in[7];  const float* wk_b  = (const float*)d_in[8];
    const float* wv_w  = (const float*)d_in[9];  const float* wv_b  = (const float*)d_in[10];
    const float* wo_w  = (const float*)d_in[11]; const float* wo_b  = (const float*)d_in[12];
    const float* jp_w  = (const float*)d_in[13]; const float* jp_b  = (const float*)d_in[14];
    const float* jc_w  = (const float*)d_in[15]; const float* jc_b  = (const float*)d_in[16];
    const float* c1_w  = (const float*)d_in[17]; const float* c1_b  = (const float*)d_in[18];
    const float* c2_w  = (const float*)d_in[19]; const float* c2_b  = (const float*)d_in[20];
    const float* c3_w  = (const float*)d_in[21]; const float* c3_b  = (const float*)d_in[22];
    const float* c4_w  = (const float*)d_in[23]; const float* c4_b  = (const float*)d_in[24];

    float* ws     = (float*)d_ws;
    float* bufQ   = ws;                    // 1,024,000 (pe -> Q in place)
    float* bufK   = bufQ   + 1024000;      // 1,024,000
    float* bufV   = bufK   + 1024000;      // 1,024,000
    float* bufAtt = bufV   + 1024000;      // 1,024,000 (protein_feats)
    float* bufP   = bufAtt + 1024000;      // 1,024,000
    float* bufC   = bufP   + 1024000;      //    65,536
    float* bufA   = bufC   + 65536;        //   512,000
    float* Opart  = bufA   + 512000;       // 2,048,000 (flash partials; later reused for MLP partials)
    float* mpart  = Opart  + 2048000;      //    16,000
    float* lpart  = mpart  + 16000;        //    16,000
    float* Asum   = lpart  + 16000;        //         8
    float* cpe    = Asum   + 8;            //     1,024
    float* h1     = cpe    + 1024;         //     8,192
    float* h2     = h1     + 8192;         //     8,192
    float* h3     = h2     + 8192;         //     2,048
    // MLP split-K partials alias Opart (dead after the wo gemm):
    float* part1  = Opart;                 //  16*8192 = 131,072
    float* part2  = part1  + 131072;       //  64*8192 = 524,288
    float* part3  = part2  + 524288;       //  64*2048 = 131,072  (total 786,432 < 2,048,000)

    hipMemsetAsync(Asum, 0, (8 + 1024) * sizeof(float), stream);

    gemm2<false,false><<<250, 256, 0, stream>>>(PE,   nullptr, nullptr, nullptr, emb_w, emb_b, bufQ, 8000, 320);
    gemm2<false,false><<<250, 256, 0, stream>>>(bufQ, nullptr, nullptr, nullptr, wq_w,  wq_b,  bufQ, 8000, 128);
    gemm2<false,false><<<250, 256, 0, stream>>>(PFX,  nullptr, nullptr, nullptr, wk_w,  wk_b,  bufK, 8000, 128);
    gemm2<false,false><<<250, 256, 0, stream>>>(PFX,  nullptr, nullptr, nullptr, wv_w,  wv_b,  bufV, 8000, 128);
    flash_k<<<dim3(32, 2, 8), 256, 0, stream>>>(bufQ, bufK, bufV, Opart, mpart, lpart);
    // wo gemm with fused KV-split merge (reads Opart halves + m/l, no merge kernel)
    gemm2<false,true ><<<250, 256, 0, stream>>>(Opart, Opart + 1024000, mpart, lpart, wo_w, wo_b, bufAtt, 8000, 128);
    gemm2<true ,false><<<250, 256, 0, stream>>>(bufAtt, nullptr, nullptr, nullptr, jp_w, jp_b, bufP, 8000, 128);
    gemm2<true ,false><<<16,  256, 0, stream>>>(CF,     nullptr, nullptr, nullptr, jc_w, jc_b, bufC,  512, 128);
    sigA_k<<<dim3(32, 8), 256, 0, stream>>>(bufP, bufC, bufA, Asum);
    cp_k<<<dim3(40, 8), 256, 0, stream>>>(bufAtt, CF, bufA, cpe);
    c1_part_k<<<16, 256, 0, stream>>>(cpe, Asum, c1_w, part1);
    mlp_fin_k<1024, 16><<<32, 256, 0, stream>>>(part1, c1_b, h1);
    c2_part_k<<<64, 256, 0, stream>>>(h1, c2_w, part2);
    mlp_fin_k<1024, 64><<<32, 256, 0, stream>>>(part2, c2_b, h2);
    c3_part_k<<<16, 256, 0, stream>>>(h2, c3_w, part3);
    mlp_fin_k<256, 64><<<8, 256, 0, stream>>>(part3, c3_b, h3);
    mlp4_k<<<1, 256, 0, stream>>>(h3, c4_w, c4_b, (float*)d_out);
}